// Round 13
// baseline (503.718 us; speedup 1.0000x reference)
//
#include <hip/hip_runtime.h>
#include <cstdint>
#include <cstddef>

#define N_NODES 50000
#define M_PAD 50048    // 391 * 128, covers GEMM tile over-read
#define E_EDGES 800000
#define INCH 128
#define HID 64
#define HEADS 4
#define NHD 256      // HEADS*HID
#define NGRAPH 64
#define DCAT 640     // 128 + 256 + 256
#define NEG_SLOPE 0.2f

typedef __attribute__((ext_vector_type(8))) short bf16x8;
typedef __attribute__((ext_vector_type(4))) float f32x4;

// round-to-nearest-even fp32 -> bf16 bits
static __device__ inline unsigned short f2bf(float f) {
    unsigned int u = __float_as_uint(f);
    unsigned int r = (u + 0x7FFFu + ((u >> 16) & 1u)) >> 16;
    return (unsigned short)r;
}
static __device__ inline float bf2f(unsigned short b) {
    return __uint_as_float(((unsigned int)b) << 16);
}

// ---- fused preamble: hist + graph_offsets + psums-zero + hi/lo splits -------
#define W1N (INCH * NHD)            // 32768
#define W2N (NHD * NHD)             // 65536
#define XN  (N_NODES * INCH)        // 6.4M
#define HB  ((E_EDGES + 255) / 256)           // 3125 hist blocks
#define GB  ((N_NODES + 255) / 256)           // 196 graph_offsets blocks
#define PZB ((NGRAPH * DCAT + 255) / 256)     // 160 psums-zero blocks
#define SPB ((W1N + W2N + XN + 255) / 256)    // 25384 split blocks
#define PREPB (HB + GB + PZB + SPB)

__global__ void prep_kernel(
    const int* __restrict__ ei, const int* __restrict__ batch,
    const float* __restrict__ W1, const float* __restrict__ W2,
    const float* __restrict__ x,
    int* __restrict__ counts, int* __restrict__ goff,
    float* __restrict__ psums,
    unsigned short* __restrict__ w1thi, unsigned short* __restrict__ w1tlo,
    unsigned short* __restrict__ w2thi, unsigned short* __restrict__ w2tlo,
    unsigned short* __restrict__ xhi, unsigned short* __restrict__ xlo)
{
    const int b = blockIdx.x;
    if (b < HB) {                               // ---- histogram of dst ----
        const int e = b * 256 + threadIdx.x;
        if (e < E_EDGES) atomicAdd(&counts[ei[E_EDGES + e]], 1);
        return;
    }
    if (b < HB + GB) {                          // ---- graph offsets ----
        const int n = (b - HB) * 256 + threadIdx.x;
        if (n >= N_NODES) return;
        const int bb = batch[n];
        const int bp = (n == 0) ? -1 : batch[n - 1];
        for (int g = bp + 1; g <= bb; ++g) goff[g] = n;
        if (n == N_NODES - 1)
            for (int g = bb + 1; g <= NGRAPH; ++g) goff[g] = N_NODES;
        return;
    }
    if (b < HB + GB + PZB) {                    // ---- zero psums ----
        const int i = (b - HB - GB) * 256 + threadIdx.x;
        if (i < NGRAPH * DCAT) psums[i] = 0.f;
        return;
    }
    // ---- hi/lo splits: W1^T, W2^T, x ----
    const int i = (b - HB - GB - PZB) * 256 + threadIdx.x;
    float v; unsigned short* dhi; unsigned short* dlo; int idx;
    if (i < W1N) {
        const int n = i / INCH, k = i - n * INCH;
        v = W1[(size_t)k * NHD + n]; dhi = w1thi; dlo = w1tlo; idx = i;
    } else if (i < W1N + W2N) {
        const int j = i - W1N;
        const int n = j / NHD, k = j - n * NHD;
        v = W2[(size_t)k * NHD + n]; dhi = w2thi; dlo = w2tlo; idx = j;
    } else {
        const int j = i - W1N - W2N;
        if (j >= XN) return;
        v = x[j]; dhi = xhi; dlo = xlo; idx = j;
    }
    const unsigned short h = f2bf(v);
    dhi[idx] = h;
    dlo[idx] = f2bf(v - bf2f(h));
}

// ------- MFMA GEMM (3-pass): Cb[M,256] = (Ahi+Alo) @ (Bhi+Blo) ---------------
// Full-N tile: A fetched once per GEMM. 4 waves of 64x128; GK=32.
#define GK 32
#define LDA 40   // LDS row stride (80B: b128 reads 2-way aliasing = free)

__global__ __launch_bounds__(256, 2) void gemm_mfma(
    const unsigned short* __restrict__ Athi,
    const unsigned short* __restrict__ Atlo,
    const unsigned short* __restrict__ Bthi,
    const unsigned short* __restrict__ Btlo,
    const float* __restrict__ asrc, const float* __restrict__ adst,
    unsigned short* __restrict__ Cb, float* __restrict__ es,
    float* __restrict__ ed, int M, int K)
{
    __shared__ unsigned short Ahi[128 * LDA];
    __shared__ unsigned short Alo[128 * LDA];
    __shared__ unsigned short Bhi[256 * LDA];
    __shared__ unsigned short Blo[256 * LDA];

    const int t    = threadIdx.x;
    const int row0 = blockIdx.x * 128;
    const int wave = t >> 6, lane = t & 63;
    const int wr  = (wave >> 1) * 64;     // wave row offset (0/64)
    const int wc2 = (wave & 1) * 128;     // wave col offset (0/128)
    const int m16 = lane & 15, quad = lane >> 4;

    f32x4 acc[4][8];
#pragma unroll
    for (int i = 0; i < 4; ++i)
#pragma unroll
        for (int j = 0; j < 8; ++j) acc[i][j] = (f32x4){0.f, 0.f, 0.f, 0.f};

    for (int k0 = 0; k0 < K; k0 += GK) {
#pragma unroll
        for (int i = 0; i < 2; ++i) {
            const int seg = t + i * 256;         // 512 segs of 8 bf16
            const int r = seg >> 2, p = (seg & 3) * 8;
            const size_t ga = (size_t)(row0 + r) * K + k0 + p;
            *(int4*)(&Ahi[r * LDA + p]) = *(const int4*)(Athi + ga);
            *(int4*)(&Alo[r * LDA + p]) = *(const int4*)(Atlo + ga);
        }
#pragma unroll
        for (int i = 0; i < 4; ++i) {
            const int seg = t + i * 256;         // 1024 segs of 8 bf16
            const int r = seg >> 2, p = (seg & 3) * 8;
            const size_t gb = (size_t)r * K + k0 + p;
            *(int4*)(&Bhi[r * LDA + p]) = *(const int4*)(Bthi + gb);
            *(int4*)(&Blo[r * LDA + p]) = *(const int4*)(Btlo + gb);
        }
        __syncthreads();

        bf16x8 afh[4], afl[4];
#pragma unroll
        for (int i = 0; i < 4; ++i) {
            const int r = wr + i * 16 + m16;
            afh[i] = *(const bf16x8*)(&Ahi[r * LDA + quad * 8]);
            afl[i] = *(const bf16x8*)(&Alo[r * LDA + quad * 8]);
        }
#pragma unroll
        for (int j = 0; j < 8; ++j) {
            const int n = wc2 + j * 16 + m16;
            const bf16x8 bh = *(const bf16x8*)(&Bhi[n * LDA + quad * 8]);
            const bf16x8 bl = *(const bf16x8*)(&Blo[n * LDA + quad * 8]);
#pragma unroll
            for (int i = 0; i < 4; ++i) {
                acc[i][j] = __builtin_amdgcn_mfma_f32_16x16x32_bf16(afh[i], bh, acc[i][j], 0, 0, 0);
                acc[i][j] = __builtin_amdgcn_mfma_f32_16x16x32_bf16(afh[i], bl, acc[i][j], 0, 0, 0);
                acc[i][j] = __builtin_amdgcn_mfma_f32_16x16x32_bf16(afl[i], bh, acc[i][j], 0, 0, 0);
            }
        }
        __syncthreads();
    }

    // ---- epilogue 1: bf16 C store (C/D layout col=lane&15, row=quad*4+reg)
#pragma unroll
    for (int i = 0; i < 4; ++i)
#pragma unroll
        for (int reg = 0; reg < 4; ++reg) {
            const int r = row0 + wr + i * 16 + quad * 4 + reg;
            if (r < M) {
#pragma unroll
                for (int j = 0; j < 8; ++j)
                    Cb[(size_t)r * NHD + wc2 + j * 16 + m16] = f2bf(acc[i][j][reg]);
            }
        }

    // ---- epilogue 2: fused attention coefficients, 2 heads per wave ----
    const int hbase = wc2 >> 6;     // heads hbase, hbase+1
    float a_s0[4], a_d0[4], a_s1[4], a_d1[4];
#pragma unroll
    for (int j = 0; j < 4; ++j) {
        a_s0[j] = asrc[hbase * HID + j * 16 + m16];
        a_d0[j] = adst[hbase * HID + j * 16 + m16];
        a_s1[j] = asrc[(hbase + 1) * HID + j * 16 + m16];
        a_d1[j] = adst[(hbase + 1) * HID + j * 16 + m16];
    }
#pragma unroll
    for (int i = 0; i < 4; ++i)
#pragma unroll
        for (int reg = 0; reg < 4; ++reg) {
            float ps0 = 0.f, pd0 = 0.f, ps1 = 0.f, pd1 = 0.f;
#pragma unroll
            for (int j = 0; j < 4; ++j) {
                const float v0 = acc[i][j][reg];
                const float v1 = acc[i][j + 4][reg];
                ps0 += v0 * a_s0[j];
                pd0 += v0 * a_d0[j];
                ps1 += v1 * a_s1[j];
                pd1 += v1 * a_d1[j];
            }
#pragma unroll
            for (int off = 1; off < 16; off <<= 1) {
                ps0 += __shfl_xor(ps0, off, 64);
                pd0 += __shfl_xor(pd0, off, 64);
                ps1 += __shfl_xor(ps1, off, 64);
                pd1 += __shfl_xor(pd1, off, 64);
            }
            if (m16 == 0) {
                const int r = row0 + wr + i * 16 + quad * 4 + reg;
                if (r < M) {
                    es[r * HEADS + hbase]     = ps0;
                    ed[r * HEADS + hbase]     = pd0;
                    es[r * HEADS + hbase + 1] = ps1;
                    ed[r * HEADS + hbase + 1] = pd1;
                }
            }
        }
}

// ------- MFMA GEMM v2 (2-pass): Cb[M,256] = A(bf16) @ (Bhi+Blo) --------------
// Layer-2 variant: A is plain bf16 (h1's lo channel dropped). LDS 51.2 KB ->
// 3 blocks/CU. 1/3 fewer MFMAs, half the A staging.
__global__ __launch_bounds__(256, 3) void gemm_mfma2(
    const unsigned short* __restrict__ At,
    const unsigned short* __restrict__ Bthi,
    const unsigned short* __restrict__ Btlo,
    const float* __restrict__ asrc, const float* __restrict__ adst,
    unsigned short* __restrict__ Cb, float* __restrict__ es,
    float* __restrict__ ed, int M, int K)
{
    __shared__ unsigned short Ash[128 * LDA];
    __shared__ unsigned short Bhi[256 * LDA];
    __shared__ unsigned short Blo[256 * LDA];

    const int t    = threadIdx.x;
    const int row0 = blockIdx.x * 128;
    const int wave = t >> 6, lane = t & 63;
    const int wr  = (wave >> 1) * 64;
    const int wc2 = (wave & 1) * 128;
    const int m16 = lane & 15, quad = lane >> 4;

    f32x4 acc[4][8];
#pragma unroll
    for (int i = 0; i < 4; ++i)
#pragma unroll
        for (int j = 0; j < 8; ++j) acc[i][j] = (f32x4){0.f, 0.f, 0.f, 0.f};

    for (int k0 = 0; k0 < K; k0 += GK) {
#pragma unroll
        for (int i = 0; i < 2; ++i) {
            const int seg = t + i * 256;         // 512 segs of 8 bf16
            const int r = seg >> 2, p = (seg & 3) * 8;
            *(int4*)(&Ash[r * LDA + p]) = *(const int4*)(At + (size_t)(row0 + r) * K + k0 + p);
        }
#pragma unroll
        for (int i = 0; i < 4; ++i) {
            const int seg = t + i * 256;         // 1024 segs of 8 bf16
            const int r = seg >> 2, p = (seg & 3) * 8;
            const size_t gb = (size_t)r * K + k0 + p;
            *(int4*)(&Bhi[r * LDA + p]) = *(const int4*)(Bthi + gb);
            *(int4*)(&Blo[r * LDA + p]) = *(const int4*)(Btlo + gb);
        }
        __syncthreads();

        bf16x8 af[4];
#pragma unroll
        for (int i = 0; i < 4; ++i) {
            const int r = wr + i * 16 + m16;
            af[i] = *(const bf16x8*)(&Ash[r * LDA + quad * 8]);
        }
#pragma unroll
        for (int j = 0; j < 8; ++j) {
            const int n = wc2 + j * 16 + m16;
            const bf16x8 bh = *(const bf16x8*)(&Bhi[n * LDA + quad * 8]);
            const bf16x8 bl = *(const bf16x8*)(&Blo[n * LDA + quad * 8]);
#pragma unroll
            for (int i = 0; i < 4; ++i) {
                acc[i][j] = __builtin_amdgcn_mfma_f32_16x16x32_bf16(af[i], bh, acc[i][j], 0, 0, 0);
                acc[i][j] = __builtin_amdgcn_mfma_f32_16x16x32_bf16(af[i], bl, acc[i][j], 0, 0, 0);
            }
        }
        __syncthreads();
    }

#pragma unroll
    for (int i = 0; i < 4; ++i)
#pragma unroll
        for (int reg = 0; reg < 4; ++reg) {
            const int r = row0 + wr + i * 16 + quad * 4 + reg;
            if (r < M) {
#pragma unroll
                for (int j = 0; j < 8; ++j)
                    Cb[(size_t)r * NHD + wc2 + j * 16 + m16] = f2bf(acc[i][j][reg]);
            }
        }

    const int hbase = wc2 >> 6;
    float a_s0[4], a_d0[4], a_s1[4], a_d1[4];
#pragma unroll
    for (int j = 0; j < 4; ++j) {
        a_s0[j] = asrc[hbase * HID + j * 16 + m16];
        a_d0[j] = adst[hbase * HID + j * 16 + m16];
        a_s1[j] = asrc[(hbase + 1) * HID + j * 16 + m16];
        a_d1[j] = adst[(hbase + 1) * HID + j * 16 + m16];
    }
#pragma unroll
    for (int i = 0; i < 4; ++i)
#pragma unroll
        for (int reg = 0; reg < 4; ++reg) {
            float ps0 = 0.f, pd0 = 0.f, ps1 = 0.f, pd1 = 0.f;
#pragma unroll
            for (int j = 0; j < 4; ++j) {
                const float v0 = acc[i][j][reg];
                const float v1 = acc[i][j + 4][reg];
                ps0 += v0 * a_s0[j];
                pd0 += v0 * a_d0[j];
                ps1 += v1 * a_s1[j];
                pd1 += v1 * a_d1[j];
            }
#pragma unroll
            for (int off = 1; off < 16; off <<= 1) {
                ps0 += __shfl_xor(ps0, off, 64);
                pd0 += __shfl_xor(pd0, off, 64);
                ps1 += __shfl_xor(ps1, off, 64);
                pd1 += __shfl_xor(pd1, off, 64);
            }
            if (m16 == 0) {
                const int r = row0 + wr + i * 16 + quad * 4 + reg;
                if (r < M) {
                    es[r * HEADS + hbase]     = ps0;
                    ed[r * HEADS + hbase]     = pd0;
                    es[r * HEADS + hbase + 1] = ps1;
                    ed[r * HEADS + hbase + 1] = pd1;
                }
            }
        }
}

// ------------------------------ CSR scan ------------------------------------
#define SBLK 1024
#define NSCB ((N_NODES + SBLK - 1) / SBLK)   // 49

__global__ __launch_bounds__(1024) void scan_local_kernel(
    const int* __restrict__ counts, int* __restrict__ offsets,
    int* __restrict__ bsum)
{
    __shared__ int tmp[SBLK];
    const int t = threadIdx.x;
    const int i = blockIdx.x * SBLK + t;
    const int v = (i < N_NODES) ? counts[i] : 0;
    tmp[t] = v;
    __syncthreads();
    for (int off = 1; off < SBLK; off <<= 1) {
        const int u = (t >= off) ? tmp[t - off] : 0;
        __syncthreads();
        tmp[t] += u;
        __syncthreads();
    }
    if (i < N_NODES) offsets[i] = tmp[t] - v;    // local exclusive prefix
    if (t == SBLK - 1) bsum[blockIdx.x] = tmp[t];
}

__global__ __launch_bounds__(1024) void scan_final_kernel(
    int* __restrict__ offsets, int* __restrict__ cursor,
    const int* __restrict__ bsum)
{
    __shared__ int base_sh;
    const int b = blockIdx.x;
    if (threadIdx.x == 0) {
        int s = 0;
        for (int j = 0; j < b; ++j) s += bsum[j];
        base_sh = s;
    }
    __syncthreads();
    const int i = b * SBLK + threadIdx.x;
    if (i < N_NODES) {
        const int v = offsets[i] + base_sh;
        offsets[i] = v;
        cursor[i]  = v;
    }
    if (b == 0 && threadIdx.x == 0) offsets[N_NODES] = E_EDGES;
}

// scatter: csr holds the SRC node id directly
__global__ void scatter_kernel(const int* __restrict__ ei, int* __restrict__ cursor,
                               int* __restrict__ csr)
{
    const int e = blockIdx.x * 256 + threadIdx.x;
    if (e >= E_EDGES) return;
    const int s = ei[e];
    const int d = ei[E_EDGES + e];
    const int pos = atomicAdd(&cursor[d], 1);
    csr[pos] = s;
}

// ------- fused softmax + aggregation: one wave per dst node ------------------
__global__ __launch_bounds__(256) void aggregate_fused(
    const unsigned short* __restrict__ hb, const int* __restrict__ csr,
    const int* __restrict__ offsets,
    const float* __restrict__ es, const float* __restrict__ ed,
    const float* __restrict__ bias, unsigned short* __restrict__ outhi)
{
    const int wid  = threadIdx.x >> 6;
    const int lane = threadIdx.x & 63;
    const int node = blockIdx.x * 4 + wid;
    if (node >= N_NODES) return;
    const int head = lane >> 4;          // col = lane*4 -> head = col/64
    const int col  = lane * 4;
    const int sub  = lane & 15;          // edge slot within 16-edge chunk

    const float edc = ed[node * 4 + head];
    const int beg = offsets[node], end = offsets[node + 1];

    float4 acc = make_float4(0.f, 0.f, 0.f, 0.f);
    float dsum = 0.f;

    int base = beg;
    int m_cur = min(16, end - base);
    int s_cur = 0; float w_cur = 0.f;
    if (base < end && sub < m_cur) {
        s_cur = csr[base + sub];
        float u = es[s_cur * 4 + head] + edc;
        u = u > 0.f ? u : NEG_SLOPE * u;
        w_cur = expf(u);
    }

    while (base < end) {
        const int base_n = base + 16;
        const int m_nxt = min(16, end - base_n);
        int s_nxt = 0; float w_nxt = 0.f;
        if (base_n < end && sub < m_nxt) {
            s_nxt = csr[base_n + sub];
            float u = es[s_nxt * 4 + head] + edc;
            u = u > 0.f ? u : NEG_SLOPE * u;
            w_nxt = expf(u);
        }
        if (m_cur == 16) {
#pragma unroll
            for (int i = 0; i < 16; ++i) {
                const int   s = (int)__builtin_amdgcn_readlane((unsigned)s_cur, i);
                const float w = __shfl(w_cur, (lane & 48) + i, 64);
                const ushort4 v = *(const ushort4*)(hb + (size_t)s * NHD + col);
                acc.x += w * bf2f(v.x);
                acc.y += w * bf2f(v.y);
                acc.z += w * bf2f(v.z);
                acc.w += w * bf2f(v.w);
                dsum += w;
            }
        } else {
            for (int i = 0; i < m_cur; ++i) {
                const int   s = __shfl(s_cur, i, 64);
                const float w = __shfl(w_cur, (lane & 48) + i, 64);
                const ushort4 v = *(const ushort4*)(hb + (size_t)s * NHD + col);
                acc.x += w * bf2f(v.x);
                acc.y += w * bf2f(v.y);
                acc.z += w * bf2f(v.z);
                acc.w += w * bf2f(v.w);
                dsum += w;
            }
        }
        s_cur = s_nxt; w_cur = w_nxt; m_cur = m_nxt; base = base_n;
    }

    const float inv = 1.0f / (dsum + 1e-16f);
    const float4 bb = *(const float4*)(bias + col);
    float4 o;
    o.x = fmaxf(acc.x * inv + bb.x, 0.f);
    o.y = fmaxf(acc.y * inv + bb.y, 0.f);
    o.z = fmaxf(acc.z * inv + bb.z, 0.f);
    o.w = fmaxf(acc.w * inv + bb.w, 0.f);
    ushort4 oh;
    oh.x = f2bf(o.x); oh.y = f2bf(o.y); oh.z = f2bf(o.z); oh.w = f2bf(o.w);
    *(ushort4*)(outhi + (size_t)node * NHD + col) = oh;
}

// ------------------------------ pooling (all-bf16 sources) -------------------
#define PRB 128

__global__ __launch_bounds__(640) void pool_sum_kernel(
    const unsigned short* __restrict__ xhi, const unsigned short* __restrict__ h1b,
    const unsigned short* __restrict__ h2b, const int* __restrict__ batch,
    float* __restrict__ sums)
{
    __shared__ int bsh[PRB];
    const int c  = threadIdx.x;            // 0..639
    const int r0 = blockIdx.x * PRB;
    const int r1 = min(N_NODES, r0 + PRB);
    const int nr = r1 - r0;
    if (c < nr) bsh[c] = batch[r0 + c];
    __syncthreads();

    const unsigned short* srcb; int ld, cc;
    if (c < INCH)            { srcb = xhi; ld = INCH; cc = c; }
    else if (c < INCH + NHD) { srcb = h1b; ld = NHD;  cc = c - INCH; }
    else                     { srcb = h2b; ld = NHD;  cc = c - INCH - NHD; }

    float sum = 0.f;
    int g = bsh[0];
    for (int i = 0; i < nr; ++i) {
        const int gb = bsh[i];
        if (gb != g) {
            atomicAdd(&sums[g * DCAT + c], sum);
            sum = 0.f;
            g = gb;
        }
        sum += bf2f(srcb[(size_t)(r0 + i) * ld + cc]);
    }
    atomicAdd(&sums[g * DCAT + c], sum);
}

// --------------- MLP head: 8 graphs per block, 8 blocks ----------------------
__global__ __launch_bounds__(256) void mlp_kernel(
    const float* __restrict__ psums, const int* __restrict__ goff,
    const float* __restrict__ W3, const float* __restrict__ b3,
    const float* __restrict__ W4, const float* __restrict__ b4,
    float* __restrict__ out)
{
    const int g0 = blockIdx.x * 8;
    __shared__ float p[8][DCAT];    // 20 KB
    __shared__ float hm[8][256];    // 8 KB
    for (int idx = threadIdx.x; idx < 8 * DCAT; idx += 256) {
        const int gg = idx / DCAT, i = idx - gg * DCAT;
        const int g = g0 + gg;
        const float inv = 1.0f / fmaxf((float)(goff[g + 1] - goff[g]), 1.0f);
        p[gg][i] = psums[(size_t)g * DCAT + i] * inv;
    }
    __syncthreads();
    const int c = threadIdx.x;
    float acc[8];
#pragma unroll
    for (int gg = 0; gg < 8; ++gg) acc[gg] = b3[c];
    for (int k = 0; k < DCAT; ++k) {
        const float w = W3[(size_t)k * 256 + c];
#pragma unroll
        for (int gg = 0; gg < 8; ++gg) acc[gg] += p[gg][k] * w;
    }
#pragma unroll
    for (int gg = 0; gg < 8; ++gg) hm[gg][c] = fmaxf(acc[gg], 0.f);
    __syncthreads();
    const int c2 = threadIdx.x & 127;
    const int gh = (threadIdx.x >> 7) * 4;   // 0 or 4
    float a2[4];
#pragma unroll
    for (int j = 0; j < 4; ++j) a2[j] = b4[c2];
    for (int k = 0; k < 256; ++k) {
        const float w = W4[(size_t)k * 128 + c2];
#pragma unroll
        for (int j = 0; j < 4; ++j) a2[j] += hm[gh + j][k] * w;
    }
#pragma unroll
    for (int j = 0; j < 4; ++j)
        out[(size_t)(g0 + gh + j) * 128 + c2] = a2[j];
}

// ------------------------------ launch --------------------------------------
extern "C" void kernel_launch(void* const* d_in, const int* in_sizes, int n_in,
                              void* d_out, int out_size, void* d_ws, size_t ws_size,
                              hipStream_t stream)
{
    const float* x     = (const float*)d_in[0];
    const int*   ei    = (const int*)d_in[1];
    const int*   batch = (const int*)d_in[2];
    const float* W1    = (const float*)d_in[3];
    const float* a1s   = (const float*)d_in[4];
    const float* a1d   = (const float*)d_in[5];
    const float* b1    = (const float*)d_in[6];
    const float* W2    = (const float*)d_in[7];
    const float* a2s   = (const float*)d_in[8];
    const float* a2d   = (const float*)d_in[9];
    const float* b2    = (const float*)d_in[10];
    const float* W3    = (const float*)d_in[11];
    const float* b3    = (const float*)d_in[12];
    const float* W4    = (const float*)d_in[13];
    const float* b4    = (const float*)d_in[14];
    float* out = (float*)d_out;

    // workspace carve
    size_t off = 0;
    auto carve = [&](size_t bytes) -> void* {
        void* p = (char*)d_ws + off;
        off = (off + bytes + 255) & ~(size_t)255;
        return p;
    };
    unsigned short* xhi   = (unsigned short*)carve((size_t)M_PAD * INCH * 2);
    unsigned short* xlo   = (unsigned short*)carve((size_t)M_PAD * INCH * 2);
    unsigned short* ghi   = (unsigned short*)carve((size_t)N_NODES * NHD * 2);  // GEMM out (gather src)
    unsigned short* h1hi  = (unsigned short*)carve((size_t)M_PAD * NHD * 2);
    unsigned short* h2hi  = (unsigned short*)carve((size_t)N_NODES * NHD * 2);
    float* es     = (float*)carve((size_t)N_NODES * HEADS * 4);
    float* ed     = (float*)carve((size_t)N_NODES * HEADS * 4);
    float* psums  = (float*)carve((size_t)NGRAPH * DCAT * 4);
    int*   counts  = (int*)carve((size_t)N_NODES * 4);
    int*   offsets = (int*)carve((size_t)(N_NODES + 1) * 4);
    int*   cursor  = (int*)carve((size_t)N_NODES * 4);
    int*   csr     = (int*)carve((size_t)E_EDGES * 4);
    int*   goff    = (int*)carve((size_t)(NGRAPH + 1) * 4);
    int*   bsum    = (int*)carve((size_t)NSCB * 4);
    unsigned short* w1thi = (unsigned short*)carve((size_t)NHD * INCH * 2);
    unsigned short* w1tlo = (unsigned short*)carve((size_t)NHD * INCH * 2);
    unsigned short* w2thi = (unsigned short*)carve((size_t)NHD * NHD * 2);
    unsigned short* w2tlo = (unsigned short*)carve((size_t)NHD * NHD * 2);

    const int egrid = (E_EDGES + 255) / 256;

    // ---- preamble: histogram + graph offsets + psums zero + splits ----
    hipMemsetAsync(counts, 0, (size_t)N_NODES * 4, stream);
    prep_kernel<<<PREPB, 256, 0, stream>>>(ei, batch, W1, W2, x,
                                           counts, goff, psums,
                                           w1thi, w1tlo, w2thi, w2tlo, xhi, xlo);
    scan_local_kernel<<<NSCB, SBLK, 0, stream>>>(counts, offsets, bsum);
    scan_final_kernel<<<NSCB, SBLK, 0, stream>>>(offsets, cursor, bsum);
    scatter_kernel<<<egrid, 256, 0, stream>>>(ei, cursor, csr);

    const int ggrid = M_PAD / 128;   // 391, full-N tile

    // ---- layer 1 (3-pass GEMM: x at full fp32 precision) ----
    gemm_mfma<<<ggrid, 256, 0, stream>>>(xhi, xlo, w1thi, w1tlo, a1s, a1d,
                                         ghi, es, ed, N_NODES, INCH);
    aggregate_fused<<<(N_NODES + 3) / 4, 256, 0, stream>>>(ghi, csr, offsets,
                                                           es, ed, b1, h1hi);
    // ---- layer 2 (2-pass GEMM: h1 as plain bf16) ----
    gemm_mfma2<<<ggrid, 256, 0, stream>>>(h1hi, w2thi, w2tlo, a2s, a2d,
                                          ghi, es, ed, N_NODES, NHD);
    aggregate_fused<<<(N_NODES + 3) / 4, 256, 0, stream>>>(ghi, csr, offsets,
                                                           es, ed, b2, h2hi);

    // ---- pooling + MLP ----
    pool_sum_kernel<<<(N_NODES + PRB - 1) / PRB, 640, 0, stream>>>(xhi, h1hi, h2hi, batch, psums);
    mlp_kernel<<<NGRAPH / 8, 256, 0, stream>>>(psums, goff, W3, b3, W4, b4, out);
}

// Round 14
// 438.536 us; speedup vs baseline: 1.1486x; 1.1486x over previous
//
#include <hip/hip_runtime.h>
#include <cstdint>
#include <cstddef>

#define N_NODES 50000
#define M_PAD 50048    // 391 * 128, covers GEMM tile over-read
#define E_EDGES 800000
#define INCH 128
#define HID 64
#define HEADS 4
#define NHD 256      // HEADS*HID
#define NGRAPH 64
#define DCAT 640     // 128 + 256 + 256
#define NEG_SLOPE 0.2f

typedef __attribute__((ext_vector_type(8))) short bf16x8;
typedef __attribute__((ext_vector_type(4))) float f32x4;

// round-to-nearest-even fp32 -> bf16 bits
static __device__ inline unsigned short f2bf(float f) {
    unsigned int u = __float_as_uint(f);
    unsigned int r = (u + 0x7FFFu + ((u >> 16) & 1u)) >> 16;
    return (unsigned short)r;
}
static __device__ inline float bf2f(unsigned short b) {
    return __uint_as_float(((unsigned int)b) << 16);
}

// ---- fused preamble: hist + graph_offsets + psums-zero + hi/lo splits -------
#define W1N (INCH * NHD)            // 32768
#define W2N (NHD * NHD)             // 65536
#define XN  (N_NODES * INCH)        // 6.4M
#define HB  ((E_EDGES + 255) / 256)           // 3125 hist blocks
#define GB  ((N_NODES + 255) / 256)           // 196 graph_offsets blocks
#define PZB ((NGRAPH * DCAT + 255) / 256)     // 160 psums-zero blocks
#define SPB ((W1N + W2N + XN + 255) / 256)    // 25384 split blocks
#define PREPB (HB + GB + PZB + SPB)

__global__ void prep_kernel(
    const int* __restrict__ ei, const int* __restrict__ batch,
    const float* __restrict__ W1, const float* __restrict__ W2,
    const float* __restrict__ x,
    int* __restrict__ counts, int* __restrict__ goff,
    float* __restrict__ psums,
    unsigned short* __restrict__ w1thi, unsigned short* __restrict__ w1tlo,
    unsigned short* __restrict__ w2thi, unsigned short* __restrict__ w2tlo,
    unsigned short* __restrict__ xhi, unsigned short* __restrict__ xlo)
{
    const int b = blockIdx.x;
    if (b < HB) {                               // ---- histogram of dst ----
        const int e = b * 256 + threadIdx.x;
        if (e < E_EDGES) atomicAdd(&counts[ei[E_EDGES + e]], 1);
        return;
    }
    if (b < HB + GB) {                          // ---- graph offsets ----
        const int n = (b - HB) * 256 + threadIdx.x;
        if (n >= N_NODES) return;
        const int bb = batch[n];
        const int bp = (n == 0) ? -1 : batch[n - 1];
        for (int g = bp + 1; g <= bb; ++g) goff[g] = n;
        if (n == N_NODES - 1)
            for (int g = bb + 1; g <= NGRAPH; ++g) goff[g] = N_NODES;
        return;
    }
    if (b < HB + GB + PZB) {                    // ---- zero psums ----
        const int i = (b - HB - GB) * 256 + threadIdx.x;
        if (i < NGRAPH * DCAT) psums[i] = 0.f;
        return;
    }
    // ---- hi/lo splits: W1^T, W2^T, x ----
    const int i = (b - HB - GB - PZB) * 256 + threadIdx.x;
    float v; unsigned short* dhi; unsigned short* dlo; int idx;
    if (i < W1N) {
        const int n = i / INCH, k = i - n * INCH;
        v = W1[(size_t)k * NHD + n]; dhi = w1thi; dlo = w1tlo; idx = i;
    } else if (i < W1N + W2N) {
        const int j = i - W1N;
        const int n = j / NHD, k = j - n * NHD;
        v = W2[(size_t)k * NHD + n]; dhi = w2thi; dlo = w2tlo; idx = j;
    } else {
        const int j = i - W1N - W2N;
        if (j >= XN) return;
        v = x[j]; dhi = xhi; dlo = xlo; idx = j;
    }
    const unsigned short h = f2bf(v);
    dhi[idx] = h;
    dlo[idx] = f2bf(v - bf2f(h));
}

// ------- MFMA GEMM (3-pass): Cb[M,256] = (Ahi+Alo) @ (Bhi+Blo) ---------------
// Full-N tile: A fetched once per GEMM. 4 waves of 64x128; GK=32.
#define GK 32
#define LDA 40   // LDS row stride (80B: b128 reads 2-way aliasing = free)

__global__ __launch_bounds__(256, 2) void gemm_mfma(
    const unsigned short* __restrict__ Athi,
    const unsigned short* __restrict__ Atlo,
    const unsigned short* __restrict__ Bthi,
    const unsigned short* __restrict__ Btlo,
    const float* __restrict__ asrc, const float* __restrict__ adst,
    unsigned short* __restrict__ Cb, float* __restrict__ es,
    float* __restrict__ ed, int M, int K)
{
    __shared__ unsigned short Ahi[128 * LDA];
    __shared__ unsigned short Alo[128 * LDA];
    __shared__ unsigned short Bhi[256 * LDA];
    __shared__ unsigned short Blo[256 * LDA];

    const int t    = threadIdx.x;
    const int row0 = blockIdx.x * 128;
    const int wave = t >> 6, lane = t & 63;
    const int wr  = (wave >> 1) * 64;     // wave row offset (0/64)
    const int wc2 = (wave & 1) * 128;     // wave col offset (0/128)
    const int m16 = lane & 15, quad = lane >> 4;

    f32x4 acc[4][8];
#pragma unroll
    for (int i = 0; i < 4; ++i)
#pragma unroll
        for (int j = 0; j < 8; ++j) acc[i][j] = (f32x4){0.f, 0.f, 0.f, 0.f};

    for (int k0 = 0; k0 < K; k0 += GK) {
#pragma unroll
        for (int i = 0; i < 2; ++i) {
            const int seg = t + i * 256;         // 512 segs of 8 bf16
            const int r = seg >> 2, p = (seg & 3) * 8;
            const size_t ga = (size_t)(row0 + r) * K + k0 + p;
            *(int4*)(&Ahi[r * LDA + p]) = *(const int4*)(Athi + ga);
            *(int4*)(&Alo[r * LDA + p]) = *(const int4*)(Atlo + ga);
        }
#pragma unroll
        for (int i = 0; i < 4; ++i) {
            const int seg = t + i * 256;         // 1024 segs of 8 bf16
            const int r = seg >> 2, p = (seg & 3) * 8;
            const size_t gb = (size_t)r * K + k0 + p;
            *(int4*)(&Bhi[r * LDA + p]) = *(const int4*)(Bthi + gb);
            *(int4*)(&Blo[r * LDA + p]) = *(const int4*)(Btlo + gb);
        }
        __syncthreads();

        bf16x8 afh[4], afl[4];
#pragma unroll
        for (int i = 0; i < 4; ++i) {
            const int r = wr + i * 16 + m16;
            afh[i] = *(const bf16x8*)(&Ahi[r * LDA + quad * 8]);
            afl[i] = *(const bf16x8*)(&Alo[r * LDA + quad * 8]);
        }
#pragma unroll
        for (int j = 0; j < 8; ++j) {
            const int n = wc2 + j * 16 + m16;
            const bf16x8 bh = *(const bf16x8*)(&Bhi[n * LDA + quad * 8]);
            const bf16x8 bl = *(const bf16x8*)(&Blo[n * LDA + quad * 8]);
#pragma unroll
            for (int i = 0; i < 4; ++i) {
                acc[i][j] = __builtin_amdgcn_mfma_f32_16x16x32_bf16(afh[i], bh, acc[i][j], 0, 0, 0);
                acc[i][j] = __builtin_amdgcn_mfma_f32_16x16x32_bf16(afh[i], bl, acc[i][j], 0, 0, 0);
                acc[i][j] = __builtin_amdgcn_mfma_f32_16x16x32_bf16(afl[i], bh, acc[i][j], 0, 0, 0);
            }
        }
        __syncthreads();
    }

    // ---- epilogue 1: bf16 C store (C/D layout col=lane&15, row=quad*4+reg)
#pragma unroll
    for (int i = 0; i < 4; ++i)
#pragma unroll
        for (int reg = 0; reg < 4; ++reg) {
            const int r = row0 + wr + i * 16 + quad * 4 + reg;
            if (r < M) {
#pragma unroll
                for (int j = 0; j < 8; ++j)
                    Cb[(size_t)r * NHD + wc2 + j * 16 + m16] = f2bf(acc[i][j][reg]);
            }
        }

    // ---- epilogue 2: fused attention coefficients, 2 heads per wave ----
    const int hbase = wc2 >> 6;     // heads hbase, hbase+1
    float a_s0[4], a_d0[4], a_s1[4], a_d1[4];
#pragma unroll
    for (int j = 0; j < 4; ++j) {
        a_s0[j] = asrc[hbase * HID + j * 16 + m16];
        a_d0[j] = adst[hbase * HID + j * 16 + m16];
        a_s1[j] = asrc[(hbase + 1) * HID + j * 16 + m16];
        a_d1[j] = adst[(hbase + 1) * HID + j * 16 + m16];
    }
#pragma unroll
    for (int i = 0; i < 4; ++i)
#pragma unroll
        for (int reg = 0; reg < 4; ++reg) {
            float ps0 = 0.f, pd0 = 0.f, ps1 = 0.f, pd1 = 0.f;
#pragma unroll
            for (int j = 0; j < 4; ++j) {
                const float v0 = acc[i][j][reg];
                const float v1 = acc[i][j + 4][reg];
                ps0 += v0 * a_s0[j];
                pd0 += v0 * a_d0[j];
                ps1 += v1 * a_s1[j];
                pd1 += v1 * a_d1[j];
            }
#pragma unroll
            for (int off = 1; off < 16; off <<= 1) {
                ps0 += __shfl_xor(ps0, off, 64);
                pd0 += __shfl_xor(pd0, off, 64);
                ps1 += __shfl_xor(ps1, off, 64);
                pd1 += __shfl_xor(pd1, off, 64);
            }
            if (m16 == 0) {
                const int r = row0 + wr + i * 16 + quad * 4 + reg;
                if (r < M) {
                    es[r * HEADS + hbase]     = ps0;
                    ed[r * HEADS + hbase]     = pd0;
                    es[r * HEADS + hbase + 1] = ps1;
                    ed[r * HEADS + hbase + 1] = pd1;
                }
            }
        }
}

// ------- MFMA GEMM v2 (2-pass): Cb[M,256] = A(bf16) @ (Bhi+Blo) --------------
// Layer-2 variant: A is plain bf16. LB(256,2): no VGPR spill (R13's (256,3)
// capped VGPRs at ~170 < 180 needed -> scratch spill, +20us).
__global__ __launch_bounds__(256, 2) void gemm_mfma2(
    const unsigned short* __restrict__ At,
    const unsigned short* __restrict__ Bthi,
    const unsigned short* __restrict__ Btlo,
    const float* __restrict__ asrc, const float* __restrict__ adst,
    unsigned short* __restrict__ Cb, float* __restrict__ es,
    float* __restrict__ ed, int M, int K)
{
    __shared__ unsigned short Ash[128 * LDA];
    __shared__ unsigned short Bhi[256 * LDA];
    __shared__ unsigned short Blo[256 * LDA];

    const int t    = threadIdx.x;
    const int row0 = blockIdx.x * 128;
    const int wave = t >> 6, lane = t & 63;
    const int wr  = (wave >> 1) * 64;
    const int wc2 = (wave & 1) * 128;
    const int m16 = lane & 15, quad = lane >> 4;

    f32x4 acc[4][8];
#pragma unroll
    for (int i = 0; i < 4; ++i)
#pragma unroll
        for (int j = 0; j < 8; ++j) acc[i][j] = (f32x4){0.f, 0.f, 0.f, 0.f};

    for (int k0 = 0; k0 < K; k0 += GK) {
#pragma unroll
        for (int i = 0; i < 2; ++i) {
            const int seg = t + i * 256;         // 512 segs of 8 bf16
            const int r = seg >> 2, p = (seg & 3) * 8;
            *(int4*)(&Ash[r * LDA + p]) = *(const int4*)(At + (size_t)(row0 + r) * K + k0 + p);
        }
#pragma unroll
        for (int i = 0; i < 4; ++i) {
            const int seg = t + i * 256;         // 1024 segs of 8 bf16
            const int r = seg >> 2, p = (seg & 3) * 8;
            const size_t gb = (size_t)r * K + k0 + p;
            *(int4*)(&Bhi[r * LDA + p]) = *(const int4*)(Bthi + gb);
            *(int4*)(&Blo[r * LDA + p]) = *(const int4*)(Btlo + gb);
        }
        __syncthreads();

        bf16x8 af[4];
#pragma unroll
        for (int i = 0; i < 4; ++i) {
            const int r = wr + i * 16 + m16;
            af[i] = *(const bf16x8*)(&Ash[r * LDA + quad * 8]);
        }
#pragma unroll
        for (int j = 0; j < 8; ++j) {
            const int n = wc2 + j * 16 + m16;
            const bf16x8 bh = *(const bf16x8*)(&Bhi[n * LDA + quad * 8]);
            const bf16x8 bl = *(const bf16x8*)(&Blo[n * LDA + quad * 8]);
#pragma unroll
            for (int i = 0; i < 4; ++i) {
                acc[i][j] = __builtin_amdgcn_mfma_f32_16x16x32_bf16(af[i], bh, acc[i][j], 0, 0, 0);
                acc[i][j] = __builtin_amdgcn_mfma_f32_16x16x32_bf16(af[i], bl, acc[i][j], 0, 0, 0);
            }
        }
        __syncthreads();
    }

#pragma unroll
    for (int i = 0; i < 4; ++i)
#pragma unroll
        for (int reg = 0; reg < 4; ++reg) {
            const int r = row0 + wr + i * 16 + quad * 4 + reg;
            if (r < M) {
#pragma unroll
                for (int j = 0; j < 8; ++j)
                    Cb[(size_t)r * NHD + wc2 + j * 16 + m16] = f2bf(acc[i][j][reg]);
            }
        }

    const int hbase = wc2 >> 6;
    float a_s0[4], a_d0[4], a_s1[4], a_d1[4];
#pragma unroll
    for (int j = 0; j < 4; ++j) {
        a_s0[j] = asrc[hbase * HID + j * 16 + m16];
        a_d0[j] = adst[hbase * HID + j * 16 + m16];
        a_s1[j] = asrc[(hbase + 1) * HID + j * 16 + m16];
        a_d1[j] = adst[(hbase + 1) * HID + j * 16 + m16];
    }
#pragma unroll
    for (int i = 0; i < 4; ++i)
#pragma unroll
        for (int reg = 0; reg < 4; ++reg) {
            float ps0 = 0.f, pd0 = 0.f, ps1 = 0.f, pd1 = 0.f;
#pragma unroll
            for (int j = 0; j < 4; ++j) {
                const float v0 = acc[i][j][reg];
                const float v1 = acc[i][j + 4][reg];
                ps0 += v0 * a_s0[j];
                pd0 += v0 * a_d0[j];
                ps1 += v1 * a_s1[j];
                pd1 += v1 * a_d1[j];
            }
#pragma unroll
            for (int off = 1; off < 16; off <<= 1) {
                ps0 += __shfl_xor(ps0, off, 64);
                pd0 += __shfl_xor(pd0, off, 64);
                ps1 += __shfl_xor(ps1, off, 64);
                pd1 += __shfl_xor(pd1, off, 64);
            }
            if (m16 == 0) {
                const int r = row0 + wr + i * 16 + quad * 4 + reg;
                if (r < M) {
                    es[r * HEADS + hbase]     = ps0;
                    ed[r * HEADS + hbase]     = pd0;
                    es[r * HEADS + hbase + 1] = ps1;
                    ed[r * HEADS + hbase + 1] = pd1;
                }
            }
        }
}

// ------------------------------ CSR scan ------------------------------------
#define SBLK 1024
#define NSCB ((N_NODES + SBLK - 1) / SBLK)   // 49

__global__ __launch_bounds__(1024) void scan_local_kernel(
    const int* __restrict__ counts, int* __restrict__ offsets,
    int* __restrict__ bsum)
{
    __shared__ int tmp[SBLK];
    const int t = threadIdx.x;
    const int i = blockIdx.x * SBLK + t;
    const int v = (i < N_NODES) ? counts[i] : 0;
    tmp[t] = v;
    __syncthreads();
    for (int off = 1; off < SBLK; off <<= 1) {
        const int u = (t >= off) ? tmp[t - off] : 0;
        __syncthreads();
        tmp[t] += u;
        __syncthreads();
    }
    if (i < N_NODES) offsets[i] = tmp[t] - v;    // local exclusive prefix
    if (t == SBLK - 1) bsum[blockIdx.x] = tmp[t];
}

__global__ __launch_bounds__(1024) void scan_final_kernel(
    int* __restrict__ offsets, int* __restrict__ cursor,
    const int* __restrict__ bsum)
{
    __shared__ int base_sh;
    const int b = blockIdx.x;
    if (threadIdx.x == 0) {
        int s = 0;
        for (int j = 0; j < b; ++j) s += bsum[j];
        base_sh = s;
    }
    __syncthreads();
    const int i = b * SBLK + threadIdx.x;
    if (i < N_NODES) {
        const int v = offsets[i] + base_sh;
        offsets[i] = v;
        cursor[i]  = v;
    }
    if (b == 0 && threadIdx.x == 0) offsets[N_NODES] = E_EDGES;
}

// scatter: csr holds the SRC node id directly
__global__ void scatter_kernel(const int* __restrict__ ei, int* __restrict__ cursor,
                               int* __restrict__ csr)
{
    const int e = blockIdx.x * 256 + threadIdx.x;
    if (e >= E_EDGES) return;
    const int s = ei[e];
    const int d = ei[E_EDGES + e];
    const int pos = atomicAdd(&cursor[d], 1);
    csr[pos] = s;
}

// ------- fused softmax + aggregation: one wave per dst node ------------------
__global__ __launch_bounds__(256) void aggregate_fused(
    const unsigned short* __restrict__ hb, const int* __restrict__ csr,
    const int* __restrict__ offsets,
    const float* __restrict__ es, const float* __restrict__ ed,
    const float* __restrict__ bias, unsigned short* __restrict__ outhi)
{
    const int wid  = threadIdx.x >> 6;
    const int lane = threadIdx.x & 63;
    const int node = blockIdx.x * 4 + wid;
    if (node >= N_NODES) return;
    const int head = lane >> 4;          // col = lane*4 -> head = col/64
    const int col  = lane * 4;
    const int sub  = lane & 15;          // edge slot within 16-edge chunk

    const float edc = ed[node * 4 + head];
    const int beg = offsets[node], end = offsets[node + 1];

    float4 acc = make_float4(0.f, 0.f, 0.f, 0.f);
    float dsum = 0.f;

    int base = beg;
    int m_cur = min(16, end - base);
    int s_cur = 0; float w_cur = 0.f;
    if (base < end && sub < m_cur) {
        s_cur = csr[base + sub];
        float u = es[s_cur * 4 + head] + edc;
        u = u > 0.f ? u : NEG_SLOPE * u;
        w_cur = expf(u);
    }

    while (base < end) {
        const int base_n = base + 16;
        const int m_nxt = min(16, end - base_n);
        int s_nxt = 0; float w_nxt = 0.f;
        if (base_n < end && sub < m_nxt) {
            s_nxt = csr[base_n + sub];
            float u = es[s_nxt * 4 + head] + edc;
            u = u > 0.f ? u : NEG_SLOPE * u;
            w_nxt = expf(u);
        }
        if (m_cur == 16) {
#pragma unroll
            for (int i = 0; i < 16; ++i) {
                const int   s = (int)__builtin_amdgcn_readlane((unsigned)s_cur, i);
                const float w = __shfl(w_cur, (lane & 48) + i, 64);
                const ushort4 v = *(const ushort4*)(hb + (size_t)s * NHD + col);
                acc.x += w * bf2f(v.x);
                acc.y += w * bf2f(v.y);
                acc.z += w * bf2f(v.z);
                acc.w += w * bf2f(v.w);
                dsum += w;
            }
        } else {
            for (int i = 0; i < m_cur; ++i) {
                const int   s = __shfl(s_cur, i, 64);
                const float w = __shfl(w_cur, (lane & 48) + i, 64);
                const ushort4 v = *(const ushort4*)(hb + (size_t)s * NHD + col);
                acc.x += w * bf2f(v.x);
                acc.y += w * bf2f(v.y);
                acc.z += w * bf2f(v.z);
                acc.w += w * bf2f(v.w);
                dsum += w;
            }
        }
        s_cur = s_nxt; w_cur = w_nxt; m_cur = m_nxt; base = base_n;
    }

    const float inv = 1.0f / (dsum + 1e-16f);
    const float4 bb = *(const float4*)(bias + col);
    float4 o;
    o.x = fmaxf(acc.x * inv + bb.x, 0.f);
    o.y = fmaxf(acc.y * inv + bb.y, 0.f);
    o.z = fmaxf(acc.z * inv + bb.z, 0.f);
    o.w = fmaxf(acc.w * inv + bb.w, 0.f);
    ushort4 oh;
    oh.x = f2bf(o.x); oh.y = f2bf(o.y); oh.z = f2bf(o.z); oh.w = f2bf(o.w);
    *(ushort4*)(outhi + (size_t)node * NHD + col) = oh;
}

// ------------------------------ pooling (all-bf16 sources) -------------------
#define PRB 128

__global__ __launch_bounds__(640) void pool_sum_kernel(
    const unsigned short* __restrict__ xhi, const unsigned short* __restrict__ h1b,
    const unsigned short* __restrict__ h2b, const int* __restrict__ batch,
    float* __restrict__ sums)
{
    __shared__ int bsh[PRB];
    const int c  = threadIdx.x;            // 0..639
    const int r0 = blockIdx.x * PRB;
    const int r1 = min(N_NODES, r0 + PRB);
    const int nr = r1 - r0;
    if (c < nr) bsh[c] = batch[r0 + c];
    __syncthreads();

    const unsigned short* srcb; int ld, cc;
    if (c < INCH)            { srcb = xhi; ld = INCH; cc = c; }
    else if (c < INCH + NHD) { srcb = h1b; ld = NHD;  cc = c - INCH; }
    else                     { srcb = h2b; ld = NHD;  cc = c - INCH - NHD; }

    float sum = 0.f;
    int g = bsh[0];
    for (int i = 0; i < nr; ++i) {
        const int gb = bsh[i];
        if (gb != g) {
            atomicAdd(&sums[g * DCAT + c], sum);
            sum = 0.f;
            g = gb;
        }
        sum += bf2f(srcb[(size_t)(r0 + i) * ld + cc]);
    }
    atomicAdd(&sums[g * DCAT + c], sum);
}

// --------------- MLP head: one graph per block (64 blocks) -------------------
__global__ __launch_bounds__(256) void mlp_kernel(
    const float* __restrict__ psums, const int* __restrict__ goff,
    const float* __restrict__ W3, const float* __restrict__ b3,
    const float* __restrict__ W4, const float* __restrict__ b4,
    float* __restrict__ out)
{
    const int g = blockIdx.x;
    __shared__ float p[DCAT];
    __shared__ float hm[256];
    const float inv = 1.0f / fmaxf((float)(goff[g + 1] - goff[g]), 1.0f);
    for (int i = threadIdx.x; i < DCAT; i += 256)
        p[i] = psums[(size_t)g * DCAT + i] * inv;
    __syncthreads();
    const int c = threadIdx.x;
    float s = b3[c];
    for (int k = 0; k < DCAT; ++k) s += p[k] * W3[(size_t)k * 256 + c];
    hm[c] = fmaxf(s, 0.f);
    __syncthreads();
    if (c < 128) {
        float o = b4[c];
        for (int k = 0; k < 256; ++k) o += hm[k] * W4[(size_t)k * 128 + c];
        out[(size_t)g * 128 + c] = o;
    }
}

// ------------------------------ launch --------------------------------------
extern "C" void kernel_launch(void* const* d_in, const int* in_sizes, int n_in,
                              void* d_out, int out_size, void* d_ws, size_t ws_size,
                              hipStream_t stream)
{
    const float* x     = (const float*)d_in[0];
    const int*   ei    = (const int*)d_in[1];
    const int*   batch = (const int*)d_in[2];
    const float* W1    = (const float*)d_in[3];
    const float* a1s   = (const float*)d_in[4];
    const float* a1d   = (const float*)d_in[5];
    const float* b1    = (const float*)d_in[6];
    const float* W2    = (const float*)d_in[7];
    const float* a2s   = (const float*)d_in[8];
    const float* a2d   = (const float*)d_in[9];
    const float* b2    = (const float*)d_in[10];
    const float* W3    = (const float*)d_in[11];
    const float* b3    = (const float*)d_in[12];
    const float* W4    = (const float*)d_in[13];
    const float* b4    = (const float*)d_in[14];
    float* out = (float*)d_out;

    // workspace carve
    size_t off = 0;
    auto carve = [&](size_t bytes) -> void* {
        void* p = (char*)d_ws + off;
        off = (off + bytes + 255) & ~(size_t)255;
        return p;
    };
    unsigned short* xhi   = (unsigned short*)carve((size_t)M_PAD * INCH * 2);
    unsigned short* xlo   = (unsigned short*)carve((size_t)M_PAD * INCH * 2);
    unsigned short* ghi   = (unsigned short*)carve((size_t)N_NODES * NHD * 2);  // GEMM out (gather src)
    unsigned short* h1hi  = (unsigned short*)carve((size_t)M_PAD * NHD * 2);
    unsigned short* h2hi  = (unsigned short*)carve((size_t)N_NODES * NHD * 2);
    float* es     = (float*)carve((size_t)N_NODES * HEADS * 4);
    float* ed     = (float*)carve((size_t)N_NODES * HEADS * 4);
    float* psums  = (float*)carve((size_t)NGRAPH * DCAT * 4);
    int*   counts  = (int*)carve((size_t)N_NODES * 4);
    int*   offsets = (int*)carve((size_t)(N_NODES + 1) * 4);
    int*   cursor  = (int*)carve((size_t)N_NODES * 4);
    int*   csr     = (int*)carve((size_t)E_EDGES * 4);
    int*   goff    = (int*)carve((size_t)(NGRAPH + 1) * 4);
    int*   bsum    = (int*)carve((size_t)NSCB * 4);
    unsigned short* w1thi = (unsigned short*)carve((size_t)NHD * INCH * 2);
    unsigned short* w1tlo = (unsigned short*)carve((size_t)NHD * INCH * 2);
    unsigned short* w2thi = (unsigned short*)carve((size_t)NHD * NHD * 2);
    unsigned short* w2tlo = (unsigned short*)carve((size_t)NHD * NHD * 2);

    const int egrid = (E_EDGES + 255) / 256;

    // ---- preamble: histogram + graph offsets + psums zero + splits ----
    hipMemsetAsync(counts, 0, (size_t)N_NODES * 4, stream);
    prep_kernel<<<PREPB, 256, 0, stream>>>(ei, batch, W1, W2, x,
                                           counts, goff, psums,
                                           w1thi, w1tlo, w2thi, w2tlo, xhi, xlo);
    scan_local_kernel<<<NSCB, SBLK, 0, stream>>>(counts, offsets, bsum);
    scan_final_kernel<<<NSCB, SBLK, 0, stream>>>(offsets, cursor, bsum);
    scatter_kernel<<<egrid, 256, 0, stream>>>(ei, cursor, csr);

    const int ggrid = M_PAD / 128;   // 391, full-N tile

    // ---- layer 1 (3-pass GEMM: x at full fp32 precision) ----
    gemm_mfma<<<ggrid, 256, 0, stream>>>(xhi, xlo, w1thi, w1tlo, a1s, a1d,
                                         ghi, es, ed, N_NODES, INCH);
    aggregate_fused<<<(N_NODES + 3) / 4, 256, 0, stream>>>(ghi, csr, offsets,
                                                           es, ed, b1, h1hi);
    // ---- layer 2 (2-pass GEMM: h1 as plain bf16) ----
    gemm_mfma2<<<ggrid, 256, 0, stream>>>(h1hi, w2thi, w2tlo, a2s, a2d,
                                          ghi, es, ed, N_NODES, NHD);
    aggregate_fused<<<(N_NODES + 3) / 4, 256, 0, stream>>>(ghi, csr, offsets,
                                                           es, ed, b2, h2hi);

    // ---- pooling + MLP ----
    pool_sum_kernel<<<(N_NODES + PRB - 1) / PRB, 640, 0, stream>>>(xhi, h1hi, h2hi, batch, psums);
    mlp_kernel<<<NGRAPH, 256, 0, stream>>>(psums, goff, W3, b3, W4, b4, out);
}